// Round 7
// baseline (5831.524 us; speedup 1.0000x reference)
//
#include <hip/hip_runtime.h>
#include <hip/hip_bf16.h>
#include <stdint.h>

#define B_   2
#define S_   2048
#define D_   1024
#define H_   16
#define HD_  64
#define FFD_ 4096
#define M_   4096
#define MEGF ((size_t)1048576)   // 1M floats

// ---------------------------------------------------------------------------
// ROUND 7: round-4's audited fp32 VALU pipeline, with ALL OUTPUTS FP32.
// Theory: problem is pure fp32 (reference is fp32 JAX; "bf16" in the test's
// error label is hardcoded in the f-string, not the executed dtype branch).
// All prior rounds wrote bf16 into an fp32-read buffer -> stride-2 value
// scramble -> the constant 7.21875 signature.
// ---------------------------------------------------------------------------

// Naive NT GEMM: C[m,n] = sum_k A[m,k]*W[n,k] + bias[n]
// 32x32 tile, 256 threads, 2x2 outputs/thread, fp32 throughout.
// EPI: 0 plain, 1 relu, 2 + residual R, 3 QKV split (q->Cf, k->Kb, v->Vb)
template <int EPI>
__global__ __launch_bounds__(256) void ngemm(
    const float* __restrict__ A, const float* __restrict__ W,
    const float* __restrict__ bias, float* __restrict__ Cf,
    float* __restrict__ Kb, float* __restrict__ Vb,
    const float* __restrict__ R, int M, int N, int K, int ldc) {
  __shared__ float As[32][33];
  __shared__ float Bs[32][33];
  const int t = threadIdx.x, tx = t & 15, ty = t >> 4;
  const int m0 = blockIdx.y << 5, n0 = blockIdx.x << 5;
  float a00 = 0.f, a01 = 0.f, a10 = 0.f, a11 = 0.f;
  for (int k0 = 0; k0 < K; k0 += 32) {
    __syncthreads();
    for (int i = t; i < 1024; i += 256) {
      const int r = i >> 5, c = i & 31;
      As[r][c] = A[(size_t)(m0 + r) * K + k0 + c];
      Bs[r][c] = W[(size_t)(n0 + r) * K + k0 + c];
    }
    __syncthreads();
#pragma unroll 8
    for (int kk = 0; kk < 32; ++kk) {
      const float x0 = As[2 * ty][kk], x1 = As[2 * ty + 1][kk];
      const float y0 = Bs[2 * tx][kk], y1 = Bs[2 * tx + 1][kk];
      a00 += x0 * y0; a01 += x0 * y1; a10 += x1 * y0; a11 += x1 * y1;
    }
  }
  const float v[2][2] = {{a00, a01}, {a10, a11}};
#pragma unroll
  for (int i = 0; i < 2; ++i)
#pragma unroll
    for (int j = 0; j < 2; ++j) {
      const int row = m0 + 2 * ty + i, col = n0 + 2 * tx + j;
      float z = v[i][j] + bias[col];
      if (EPI == 1) z = fmaxf(z, 0.f);
      if (EPI == 2) z += R[(size_t)row * ldc + col];
      if (EPI == 3) {
        const int seg = col >> 10, cc = col & 1023;
        const size_t o = (size_t)row * 1024 + cc;
        if (seg == 0) Cf[o] = z;
        else if (seg == 1) Kb[o] = z;
        else Vb[o] = z;
      } else {
        Cf[(size_t)row * ldc + col] = z;
      }
    }
}

// ---------------------------------------------------------------------------
// Naive causal attention, fp32. Block = (64 q-rows, head, batch), 4 waves.
// Wave w owns q-rows qb+16w..+15. Per 64-key chunk: lanes=keys for scores +
// wave softmax (shfl butterfly), lanes=d for the PV accumulate.
// ---------------------------------------------------------------------------
__global__ __launch_bounds__(256) void nattn(
    const float* __restrict__ Qf, const float* __restrict__ Kc,
    const float* __restrict__ Vc, float* __restrict__ Attn) {
  const int qt = blockIdx.x, h = blockIdx.y, b = blockIdx.z;
  const int t = threadIdx.x, w = t >> 6, l = t & 63;
  __shared__ float Qs[64][64];
  __shared__ float Ks[64][65];
  __shared__ float Vs[64][65];
  __shared__ float Ps[4][64];
  const int qb = qt << 6;

  for (int i = t; i < 4096; i += 256) {
    const int r = i >> 6, c = i & 63;
    Qs[r][c] = Qf[(size_t)(b * S_ + qb + r) * D_ + h * HD_ + c];
  }

  float m_i[16], l_i[16], oacc[16];
#pragma unroll
  for (int r = 0; r < 16; ++r) { m_i[r] = -1e30f; l_i[r] = 0.f; oacc[r] = 0.f; }

  const int nchunk = qt + 1;
  for (int kt = 0; kt < nchunk; ++kt) {
    __syncthreads();
    for (int i = t; i < 4096; i += 256) {
      const int r = i >> 6, c = i & 63;
      const size_t g = (size_t)(b * S_ + (kt << 6) + r) * D_ + h * HD_ + c;
      Ks[r][c] = Kc[g];
      Vs[r][c] = Vc[g];
    }
    __syncthreads();

#pragma unroll 1
    for (int r16 = 0; r16 < 16; ++r16) {
      const int qrow = qb + (w << 4) + r16;
      const int key = (kt << 6) + l;
      float s = 0.f;
#pragma unroll 8
      for (int d = 0; d < 64; ++d) s += Qs[(w << 4) + r16][d] * Ks[l][d];
      s *= 0.125f;
      if (key > qrow) s = -1e30f;
      float mx = s;
#pragma unroll
      for (int off = 1; off < 64; off <<= 1) mx = fmaxf(mx, __shfl_xor(mx, off, 64));
      const float mn = fmaxf(m_i[r16], mx);
      const float alpha = __expf(m_i[r16] - mn);
      const float p = __expf(s - mn);
      float sum = p;
#pragma unroll
      for (int off = 1; off < 64; off <<= 1) sum += __shfl_xor(sum, off, 64);
      m_i[r16] = mn;
      l_i[r16] = l_i[r16] * alpha + sum;
      Ps[w][l] = p;   // intra-wave LDS RAW; compiler orders via lgkmcnt
      float acc = oacc[r16] * alpha;
#pragma unroll 8
      for (int k2 = 0; k2 < 64; ++k2) acc += Ps[w][k2] * Vs[k2][l];
      oacc[r16] = acc;
    }
  }

#pragma unroll
  for (int r16 = 0; r16 < 16; ++r16) {
    const size_t o = (size_t)(b * S_ + qb + (w << 4) + r16) * D_ + h * HD_ + l;
    Attn[o] = oacc[r16] / l_i[r16];
  }
}

// ---------------------------------------------------------------------------
// LN: ADDY? LN(X+Y) : LN(X). fp32 in/out. One block per row of 1024.
// ---------------------------------------------------------------------------
template <int ADDY>
__global__ __launch_bounds__(256) void ln_f(
    const float* __restrict__ X, const float* __restrict__ Y,
    const float* __restrict__ g, const float* __restrict__ be,
    float* __restrict__ Out) {
  const int row = blockIdx.x, t = threadIdx.x;
  const size_t base = (size_t)row * D_ + t * 4;
  float v[4];
  float s = 0.f, q = 0.f;
#pragma unroll
  for (int i = 0; i < 4; ++i) {
    v[i] = X[base + i] + (ADDY ? Y[base + i] : 0.f);
    s += v[i];
    q += v[i] * v[i];
  }
#pragma unroll
  for (int off = 32; off; off >>= 1) {
    s += __shfl_down(s, off, 64);
    q += __shfl_down(q, off, 64);
  }
  __shared__ float rs[4], rq[4];
  const int w = t >> 6, l = t & 63;
  if (l == 0) { rs[w] = s; rq[w] = q; }
  __syncthreads();
  s = rs[0] + rs[1] + rs[2] + rs[3];
  q = rq[0] + rq[1] + rq[2] + rq[3];
  const float mu = s * (1.f / D_);
  const float var = q * (1.f / D_) - mu * mu;
  const float rstd = rsqrtf(var + 1e-5f);
#pragma unroll
  for (int i = 0; i < 4; ++i)
    Out[base + i] = (v[i] - mu) * rstd * g[t * 4 + i] + be[t * 4 + i];
}

extern "C" void kernel_launch(void* const* d_in, const int* in_sizes, int n_in,
                              void* d_out, int out_size, void* d_ws, size_t ws_size,
                              hipStream_t stream) {
  const float* x     = (const float*)d_in[0];
  const float* qkv_w = (const float*)d_in[1];
  const float* qkv_b = (const float*)d_in[2];
  const float* out_w = (const float*)d_in[3];
  const float* out_b = (const float*)d_in[4];
  const float* w1    = (const float*)d_in[5];
  const float* b1    = (const float*)d_in[6];
  const float* w2    = (const float*)d_in[7];
  const float* b2    = (const float*)d_in[8];
  const float* l1w   = (const float*)d_in[9];
  const float* l1b   = (const float*)d_in[10];
  const float* l2w   = (const float*)d_in[11];
  const float* l2b   = (const float*)d_in[12];

  float* out    = (float*)d_out;
  float* kcache = out + (size_t)M_ * D_;
  float* vcache = kcache + (size_t)M_ * D_;

  // ws (floats): [0,4M) q_f -> y_f -> sum_f ; [4M,8M) attn_f -> ff chunk ;
  // [8M,12M) h1_f.  High-water 48 MB (established non-factor at 24-75 MB).
  float* wsf  = (float*)d_ws;
  float* qf   = wsf;
  float* attn = wsf + 4 * MEGF;
  float* h1   = wsf + 8 * MEGF;

  const dim3 blk(256);
  // QKV: q fp32 -> qf; k,v fp32 straight to caches.
  ngemm<3><<<dim3(3 * D_ / 32, M_ / 32), blk, 0, stream>>>(
      x, qkv_w, qkv_b, qf, kcache, vcache, nullptr, M_, 3 * D_, D_, D_);
  nattn<<<dim3(S_ / 64, H_, B_), blk, 0, stream>>>(qf, kcache, vcache, attn);
  // out-proj -> y_f (reuse qf)
  ngemm<0><<<dim3(D_ / 32, M_ / 32), blk, 0, stream>>>(
      attn, out_w, out_b, qf, nullptr, nullptr, nullptr, M_, D_, D_, D_);
  // h1 = LN(x + y)
  ln_f<1><<<dim3(M_), blk, 0, stream>>>(x, qf, l1w, l1b, h1);
  // MLP in 4 chunks of 1024 rows; ff reuses attn region; sum reuses qf.
  for (int c = 0; c < 4; ++c) {
    const float* hrows = h1 + (size_t)c * 1024 * D_;
    float* srows = qf + (size_t)c * 1024 * D_;
    ngemm<1><<<dim3(FFD_ / 32, 1024 / 32), blk, 0, stream>>>(
        hrows, w1, b1, attn, nullptr, nullptr, nullptr, 1024, FFD_, D_, FFD_);
    ngemm<2><<<dim3(D_ / 32, 1024 / 32), blk, 0, stream>>>(
        attn, w2, b2, srows, nullptr, nullptr, hrows, 1024, D_, FFD_, D_);
  }
  // out = LN(sum) -> fp32
  ln_f<0><<<dim3(M_), blk, 0, stream>>>(qf, qf, l2w, l2b, out);
}

// Round 8
// 623.099 us; speedup vs baseline: 9.3589x; 9.3589x over previous
//
#include <hip/hip_runtime.h>
#include <hip/hip_bf16.h>
#include <stdint.h>

typedef __hip_bfloat16 bf16;
typedef __attribute__((ext_vector_type(8))) short s16x8;
typedef __attribute__((ext_vector_type(4))) float f32x4;

#define B_   2
#define S_   2048
#define D_   1024
#define H_   16
#define HD_  64
#define FFD_ 4096
#define M_   4096
#define MEG  ((size_t)1048576)

__device__ __forceinline__ f32x4 mfma_bf16(s16x8 a, s16x8 b, f32x4 c) {
  return __builtin_amdgcn_mfma_f32_16x16x32_bf16(a, b, c, 0, 0, 0);
}

__device__ __forceinline__ void gl_lds16(const bf16* g, bf16* l) {
  __builtin_amdgcn_global_load_lds(
      (const __attribute__((address_space(1))) void*)g,
      (__attribute__((address_space(3))) void*)l, 16, 0, 0);
}

__device__ __forceinline__ float b2f(short u) {
  union { uint32_t i; float f; } z;
  z.i = ((uint32_t)(unsigned short)u) << 16;
  return z.f;
}
__device__ __forceinline__ short f2b(float f) {
  const bf16 h = __float2bfloat16(f);
  return *(const short*)&h;
}

// ---------------------------------------------------------------------------
// fp32 -> bf16 conversion (inputs are fp32; GEMM operands need bf16).
// ---------------------------------------------------------------------------
__global__ __launch_bounds__(256) void cvt_f2b(
    const float* __restrict__ src, bf16* __restrict__ dst, int n) {
  const int idx = (blockIdx.x * 256 + threadIdx.x) * 8;
  if (idx >= n) return;
  s16x8 o;
#pragma unroll
  for (int i = 0; i < 8; ++i) o[i] = f2b(src[idx + i]);
  *(s16x8*)(dst + idx) = o;
}

// ---------------------------------------------------------------------------
// MFMA NT GEMM: C[m,n] = sum_k A[m,k]*W[n,k] + bias[n]  (bias fp32)
// 128x128 tile, BK=32, 4 waves (2x2), 4x4 16x16x32 frags.
// MODE 0: C -> bf16 Cb             (out-proj -> y1)
// MODE 1: relu, C -> bf16 Cb       (MLP1 -> ff)
// MODE 2: C + resid(bf16) -> fp32 Cf  (MLP2 -> sum in d_out)
// MODE 3: QKV split: seg0 q->bf16 Cb; seg1 k->fp32 Kf + bf16 Kb;
//         seg2 v->fp32 Vf + bf16 Vb.  All row stride 1024.
// ---------------------------------------------------------------------------
template <int MODE>
__global__ __launch_bounds__(256) void gemm_bt(
    const bf16* __restrict__ A, const bf16* __restrict__ W,
    const float* __restrict__ bias,
    bf16* __restrict__ Cb, float* __restrict__ Cf,
    float* __restrict__ Kf, bf16* __restrict__ Kb,
    float* __restrict__ Vf, bf16* __restrict__ Vb,
    const bf16* __restrict__ Res,
    int M, int N, int K) {
  __shared__ __align__(16) bf16 As[128 * 32];
  __shared__ __align__(16) bf16 Bs[128 * 32];
  const int t = threadIdx.x;
  const int m0 = blockIdx.y << 7, n0 = blockIdx.x << 7;
  const int w = t >> 6, l = t & 63;
  const int wm = (w >> 1) << 6, wn = (w & 1) << 6;
  const int l15 = l & 15, quad = l >> 4;

  f32x4 acc[4][4] = {};

  const int srow = t >> 2;          // 0..63
  const int scol = (t & 3) << 3;    // 0,8,16,24
  const bf16* Ag  = A + (size_t)(m0 + srow) * K + scol;
  const bf16* Ag2 = Ag + ((size_t)K << 6);   // +64 rows
  const bf16* Wg  = W + (size_t)(n0 + srow) * K + scol;
  const bf16* Wg2 = Wg + ((size_t)K << 6);
  bf16* Al  = As + t * 8;
  bf16* Al2 = Al + 2048;
  bf16* Bl  = Bs + t * 8;
  bf16* Bl2 = Bl + 2048;

  for (int k0 = 0; k0 < K; k0 += 32) {
    __syncthreads();
    gl_lds16(Ag + k0, Al);
    gl_lds16(Ag2 + k0, Al2);
    gl_lds16(Wg + k0, Bl);
    gl_lds16(Wg2 + k0, Bl2);
    __syncthreads();
    const s16x8* As8 = (const s16x8*)As;
    const s16x8* Bs8 = (const s16x8*)Bs;
    s16x8 af[4], bfr[4];
#pragma unroll
    for (int i = 0; i < 4; ++i) af[i]  = As8[((wm + i * 16 + l15) << 2) + quad];
#pragma unroll
    for (int i = 0; i < 4; ++i) bfr[i] = Bs8[((wn + i * 16 + l15) << 2) + quad];
#pragma unroll
    for (int mi = 0; mi < 4; ++mi)
#pragma unroll
      for (int ni = 0; ni < 4; ++ni)
        acc[mi][ni] = mfma_bf16(af[mi], bfr[ni], acc[mi][ni]);
  }

  float bv[4];
#pragma unroll
  for (int ni = 0; ni < 4; ++ni)
    bv[ni] = bias[n0 + wn + ni * 16 + l15];

  const int seg = n0 >> 10, nb = n0 & 1023;
#pragma unroll
  for (int mi = 0; mi < 4; ++mi) {
#pragma unroll
    for (int reg = 0; reg < 4; ++reg) {
      const int row = m0 + wm + mi * 16 + quad * 4 + reg;
#pragma unroll
      for (int ni = 0; ni < 4; ++ni) {
        float v = acc[mi][ni][reg] + bv[ni];
        if (MODE == 0) {
          Cb[(size_t)row * N + n0 + wn + ni * 16 + l15] = __float2bfloat16(v);
        } else if (MODE == 1) {
          v = fmaxf(v, 0.f);
          Cb[(size_t)row * N + n0 + wn + ni * 16 + l15] = __float2bfloat16(v);
        } else if (MODE == 2) {
          const size_t o = (size_t)row * N + n0 + wn + ni * 16 + l15;
          Cf[o] = v + b2f(*(const short*)&Res[o]);
        } else {  // MODE 3
          const size_t o = (size_t)row * 1024 + nb + wn + ni * 16 + l15;
          if (seg == 0) {
            Cb[o] = __float2bfloat16(v);
          } else if (seg == 1) {
            Kf[o] = v; Kb[o] = __float2bfloat16(v);
          } else {
            Vf[o] = v; Vb[o] = __float2bfloat16(v);
          }
        }
      }
    }
  }
}

// ---------------------------------------------------------------------------
// MFMA flash attention, causal, hd=64. Block = (64 q-rows, head, batch).
// Q/K/V: bf16 [M,1024] ws buffers. O: bf16 [M,1024].
// ---------------------------------------------------------------------------
__global__ __launch_bounds__(256) void flash_attn(
    const bf16* __restrict__ Q, const bf16* __restrict__ Kk,
    const bf16* __restrict__ V, bf16* __restrict__ O) {
  const int qt = blockIdx.x, h = blockIdx.y, b = blockIdx.z;
  const int t = threadIdx.x, w = t >> 6, l = t & 63;
  const int l15 = l & 15, quad = l >> 4;
  __shared__ __align__(16) bf16 Ks[64 * 64];       // [key][d]
  __shared__ __align__(16) bf16 Vt[64 * 64];       // [d][key] transposed
  __shared__ __align__(16) bf16 Ps[4][16 * 64];    // per-wave P [row][key]

  const int qb = qt << 6;
  const int qrowA = qb + (w << 4) + l15;
  const bf16* qp = Q + (size_t)(b * S_ + qrowA) * D_ + h * HD_ + quad * 8;
  const s16x8 qf0 = *(const s16x8*)qp;
  const s16x8 qf1 = *(const s16x8*)(qp + 32);

  f32x4 o[4] = {};
  float m_i[4], l_i[4];
#pragma unroll
  for (int r = 0; r < 4; ++r) { m_i[r] = -1e30f; l_i[r] = 0.f; }

  const int krow = t >> 3, kcol = (t & 7) << 3;
  const bf16* Kg  = Kk + (size_t)(b * S_ + krow) * D_ + h * HD_ + kcol;
  const bf16* Kg2 = Kg + (size_t)32 * D_;
  bf16* Kl  = Ks + t * 8;
  bf16* Kl2 = Kl + 2048;
  const int vk = t & 63, vd = (t >> 6) << 4;
  const bf16* Vg = V + (size_t)(b * S_ + vk) * D_ + h * HD_ + vd;

  const int ntiles = qt + 1;
  for (int kt = 0; kt < ntiles; ++kt) {
    const size_t koff = (size_t)(kt << 6) * D_;
    __syncthreads();
    gl_lds16(Kg + koff, Kl);
    gl_lds16(Kg2 + koff, Kl2);
    {
      const s16x8 v0 = *(const s16x8*)(Vg + koff);
      const s16x8 v1 = *(const s16x8*)(Vg + koff + 8);
      short* vtp = (short*)Vt;
#pragma unroll
      for (int j = 0; j < 8; ++j) {
        vtp[(vd + j) * 64 + vk]     = v0[j];
        vtp[(vd + 8 + j) * 64 + vk] = v1[j];
      }
    }
    __syncthreads();

    f32x4 sc[4];
#pragma unroll
    for (int ni = 0; ni < 4; ++ni) {
      const s16x8 kf0 = *(const s16x8*)&Ks[(ni * 16 + l15) * 64 + quad * 8];
      const s16x8 kf1 = *(const s16x8*)&Ks[(ni * 16 + l15) * 64 + 32 + quad * 8];
      f32x4 z = {};
      z = mfma_bf16(qf0, kf0, z);
      sc[ni] = mfma_bf16(qf1, kf1, z);
    }

    float p[4][4];
#pragma unroll
    for (int ni = 0; ni < 4; ++ni) {
      const int key = (kt << 6) + ni * 16 + l15;
#pragma unroll
      for (int reg = 0; reg < 4; ++reg) {
        const int qrow = qb + (w << 4) + quad * 4 + reg;
        const float s = sc[ni][reg] * 0.125f;
        p[ni][reg] = (key > qrow) ? -1e30f : s;
      }
    }
#pragma unroll
    for (int reg = 0; reg < 4; ++reg) {
      float mx = fmaxf(fmaxf(p[0][reg], p[1][reg]), fmaxf(p[2][reg], p[3][reg]));
#pragma unroll
      for (int off = 1; off < 16; off <<= 1)
        mx = fmaxf(mx, __shfl_xor(mx, off, 64));
      const float mn = fmaxf(m_i[reg], mx);
      const float alpha = __expf(m_i[reg] - mn);
      m_i[reg] = mn;
      float sum = 0.f;
#pragma unroll
      for (int ni = 0; ni < 4; ++ni) {
        const float e = __expf(p[ni][reg] - mn);
        p[ni][reg] = e;
        sum += e;
      }
#pragma unroll
      for (int off = 1; off < 16; off <<= 1)
        sum += __shfl_xor(sum, off, 64);
      l_i[reg] = l_i[reg] * alpha + sum;
#pragma unroll
      for (int ni = 0; ni < 4; ++ni) o[ni][reg] *= alpha;
    }

#pragma unroll
    for (int reg = 0; reg < 4; ++reg)
#pragma unroll
      for (int ni = 0; ni < 4; ++ni)
        Ps[w][(quad * 4 + reg) * 64 + ni * 16 + l15] = __float2bfloat16(p[ni][reg]);
    __syncthreads();

#pragma unroll
    for (int ks = 0; ks < 2; ++ks) {
      const s16x8 pf = *(const s16x8*)&Ps[w][l15 * 64 + ks * 32 + quad * 8];
#pragma unroll
      for (int ni = 0; ni < 4; ++ni) {
        const s16x8 vf = *(const s16x8*)&Vt[(ni * 16 + l15) * 64 + ks * 32 + quad * 8];
        o[ni] = mfma_bf16(pf, vf, o[ni]);
      }
    }
  }

#pragma unroll
  for (int reg = 0; reg < 4; ++reg) {
    const float inv = 1.f / l_i[reg];
    const int row = b * S_ + qb + (w << 4) + quad * 4 + reg;
    bf16* op = O + (size_t)row * D_ + h * HD_ + l15;
#pragma unroll
    for (int ni = 0; ni < 4; ++ni)
      op[ni * 16] = __float2bfloat16(o[ni][reg] * inv);
  }
}

// ---------------------------------------------------------------------------
// LN1: h1 = LN(x_f32 + y1_bf16) -> bf16.   LN2: out = LN(sum_f32) -> fp32
// (in place). One block per 1024-col row.
// ---------------------------------------------------------------------------
template <int MODE>   // 0: LN1, 1: LN2
__global__ __launch_bounds__(256) void add_ln(
    const float* __restrict__ X, const bf16* __restrict__ Y,
    const float* __restrict__ g, const float* __restrict__ be,
    void* Out) {
  const int row = blockIdx.x, t = threadIdx.x;
  const size_t base = (size_t)row * D_ + t * 4;
  float v[4];
  float s = 0.f, q = 0.f;
#pragma unroll
  for (int i = 0; i < 4; ++i) {
    v[i] = X[base + i];
    if (MODE == 0) v[i] += b2f(*(const short*)&Y[base + i]);
    s += v[i];
    q += v[i] * v[i];
  }
#pragma unroll
  for (int off = 32; off; off >>= 1) {
    s += __shfl_down(s, off, 64);
    q += __shfl_down(q, off, 64);
  }
  __shared__ float rs[4], rq[4];
  const int w = t >> 6, l = t & 63;
  if (l == 0) { rs[w] = s; rq[w] = q; }
  __syncthreads();
  s = rs[0] + rs[1] + rs[2] + rs[3];
  q = rq[0] + rq[1] + rq[2] + rq[3];
  const float mu = s * (1.f / D_);
  const float var = q * (1.f / D_) - mu * mu;
  const float rstd = rsqrtf(var + 1e-5f);
#pragma unroll
  for (int i = 0; i < 4; ++i) {
    const float r = (v[i] - mu) * rstd * g[t * 4 + i] + be[t * 4 + i];
    if (MODE == 0) ((bf16*)Out)[base + i] = __float2bfloat16(r);
    else           ((float*)Out)[base + i] = r;
  }
}

extern "C" void kernel_launch(void* const* d_in, const int* in_sizes, int n_in,
                              void* d_out, int out_size, void* d_ws, size_t ws_size,
                              hipStream_t stream) {
  const float* x     = (const float*)d_in[0];
  const float* qkv_b = (const float*)d_in[2];
  const float* out_b = (const float*)d_in[4];
  const float* b1    = (const float*)d_in[6];
  const float* b2    = (const float*)d_in[8];
  const float* l1w   = (const float*)d_in[9];
  const float* l1b   = (const float*)d_in[10];
  const float* l2w   = (const float*)d_in[11];
  const float* l2b   = (const float*)d_in[12];

  float* out    = (float*)d_out;
  float* kcache = out + (size_t)M_ * D_;
  float* vcache = kcache + (size_t)M_ * D_;

  // ws (bf16 elems). High-water 28M elems = 56 MB (<75 MB established safe).
  //  [0,4M)   xc      -> attnb (after QKV)
  //  [4,7M)   wqkv    -> h1 (after out-proj; h1 spans [4,8M))
  //  [7,8M)   wout
  //  [8,12M)  w1c
  //  [12,16M) w2c
  //  [16,20M) qbuf    -> y1 (after flash)
  //  [20,24M) kb      -> ffb chunk (after flash; ffb spans [20,28M))
  //  [24,28M) vb
  bf16* ws    = (bf16*)d_ws;
  bf16* xc    = ws;
  bf16* attnb = ws;
  bf16* wqkv  = ws + 4 * MEG;
  bf16* h1    = ws + 4 * MEG;
  bf16* wout  = ws + 7 * MEG;
  bf16* w1c   = ws + 8 * MEG;
  bf16* w2c   = ws + 12 * MEG;
  bf16* qbuf  = ws + 16 * MEG;
  bf16* y1    = ws + 16 * MEG;
  bf16* kb    = ws + 20 * MEG;
  bf16* ffb   = ws + 20 * MEG;
  bf16* vb    = ws + 24 * MEG;

  const dim3 blk(256);
  auto cvt = [&](const void* src, bf16* dst, int n) {
    cvt_f2b<<<dim3((n + 2047) / 2048), blk, 0, stream>>>((const float*)src, dst, n);
  };
  cvt(d_in[0], xc,   M_ * D_);
  cvt(d_in[1], wqkv, 3 * D_ * D_);
  cvt(d_in[3], wout, D_ * D_);
  cvt(d_in[5], w1c,  FFD_ * D_);
  cvt(d_in[7], w2c,  D_ * FFD_);

  // QKV: q->qbuf bf16; k/v->fp32 caches + bf16 ws copies.
  gemm_bt<3><<<dim3(3 * D_ / 128, M_ / 128), blk, 0, stream>>>(
      xc, wqkv, qkv_b, qbuf, nullptr, kcache, kb, vcache, vb, nullptr,
      M_, 3 * D_, D_);
  flash_attn<<<dim3(S_ / 64, H_, B_), blk, 0, stream>>>(qbuf, kb, vb, attnb);
  // out-proj -> y1 bf16 (overwrites dead qbuf)
  gemm_bt<0><<<dim3(D_ / 128, M_ / 128), blk, 0, stream>>>(
      attnb, wout, out_b, y1, nullptr, nullptr, nullptr, nullptr, nullptr,
      nullptr, M_, D_, D_);
  // h1 = LN(x + y1) -> bf16 (overwrites dead wqkv)
  add_ln<0><<<dim3(M_), blk, 0, stream>>>(x, y1, l1w, l1b, h1);
  // MLP, 2 chunks of 2048 rows; ffb reuses kb/vb region; sum -> d_out fp32.
  for (int c = 0; c < 2; ++c) {
    const bf16* hrows = h1 + (size_t)c * 2048 * D_;
    float* srows = out + (size_t)c * 2048 * D_;
    gemm_bt<1><<<dim3(FFD_ / 128, 2048 / 128), blk, 0, stream>>>(
        hrows, w1c, b1, ffb, nullptr, nullptr, nullptr, nullptr, nullptr,
        nullptr, 2048, FFD_, D_);
    gemm_bt<2><<<dim3(D_ / 128, 2048 / 128), blk, 0, stream>>>(
        ffb, w2c, b2, nullptr, srows, nullptr, nullptr, nullptr, nullptr,
        hrows, 2048, D_, FFD_);
  }
  // out = LN(sum) in place, fp32.
  add_ln<1><<<dim3(M_), blk, 0, stream>>>(out, nullptr, l2w, l2b, out);
}